// Round 1
// baseline (1167.844 us; speedup 1.0000x reference)
//
#include <hip/hip_runtime.h>
#include <math.h>

#define Bsz 4
#define Cch 32
#define Hh 48
#define Ww 48
#define HWsz 2304          // 48*48
#define BHW 9216           // 4*2304
#define CIN_CAT 96
#define NCHUNK 16          // column chunks for score partials
#define CHUNK_COLS 576     // 9216/16

// ---------------- bilinear resize, align_corners=True ----------------
// reads in[(b*C+c)*chanStride + baseOff + y*rowStride + x], writes into a
// (B, outCtot, 48, 48) tensor at channel offset chanOff.
__global__ void resize_kernel(const float* __restrict__ in, float* __restrict__ out,
                              int inH, int inW, int rowStride, int chanStride, int baseOff,
                              float scaleY, float scaleX, int outCtot, int chanOff) {
    int idx = blockIdx.x * blockDim.x + threadIdx.x;
    if (idx >= Bsz * Cch * HWsz) return;
    int x = idx % Ww;
    int y = (idx / Ww) % Hh;
    int c = (idx / HWsz) % Cch;
    int b = idx / (HWsz * Cch);
    float fy = y * scaleY;
    float fx = x * scaleX;
    int y0 = (int)floorf(fy); int x0 = (int)floorf(fx);
    y0 = min(y0, inH - 1); x0 = min(x0, inW - 1);
    int y1 = min(y0 + 1, inH - 1); int x1 = min(x0 + 1, inW - 1);
    float wy = fy - (float)y0, wx = fx - (float)x0;
    const float* src = in + (size_t)(b * Cch + c) * chanStride + baseOff;
    float v00 = src[y0 * rowStride + x0];
    float v01 = src[y0 * rowStride + x1];
    float v10 = src[y1 * rowStride + x0];
    float v11 = src[y1 * rowStride + x1];
    float top = v00 * (1.f - wx) + v01 * wx;
    float bot = v10 * (1.f - wx) + v11 * wx;
    float r = top * (1.f - wy) + bot * wy;
    out[((size_t)(b * outCtot) + c + chanOff) * HWsz + y * Ww + x] = r;
}

// copy x1 (B,32,HW) into cat channels [64..96)
__global__ void copy_x1_kernel(const float* __restrict__ x1, float* __restrict__ cat) {
    int idx = blockIdx.x * blockDim.x + threadIdx.x;
    if (idx >= Bsz * Cch * HWsz) return;
    int hw = idx % HWsz;
    int c = (idx / HWsz) % Cch;
    int b = idx / (HWsz * Cch);
    cat[((size_t)(b * CIN_CAT) + 64 + c) * HWsz + hw] = x1[idx];
}

// ---------------- 3x3 conv, pad 1, fused BN (+optional input add, output residual) ----
__global__ void conv3x3_kernel(const float* __restrict__ in, const float* __restrict__ in2,
                               const float* __restrict__ w, const float* __restrict__ bng,
                               const float* __restrict__ bnb, const float* __restrict__ res,
                               float* __restrict__ out, int Cin, int Cout) {
    int idx = blockIdx.x * blockDim.x + threadIdx.x;
    int total = Bsz * Cout * HWsz;
    if (idx >= total) return;
    int x = idx % Ww;
    int y = (idx / Ww) % Hh;
    int co = (idx / HWsz) % Cout;
    int b = idx / (HWsz * Cout);
    bool has2 = (in2 != nullptr);
    float acc = 0.f;
#pragma unroll
    for (int ky = 0; ky < 3; ++ky) {
        int iy = y + ky - 1;
        if (iy < 0 || iy >= Hh) continue;
#pragma unroll
        for (int kx = 0; kx < 3; ++kx) {
            int ix = x + kx - 1;
            if (ix < 0 || ix >= Ww) continue;
            int ioff = iy * Ww + ix;
            const float* wp = w + ((size_t)co * Cin) * 9 + ky * 3 + kx;
            if (has2) {
                for (int ci = 0; ci < Cin; ++ci) {
                    float v = in[((size_t)(b * Cin) + ci) * HWsz + ioff]
                            + in2[((size_t)(b * Cin) + ci) * HWsz + ioff];
                    acc += v * wp[ci * 9];
                }
            } else {
                for (int ci = 0; ci < Cin; ++ci) {
                    float v = in[((size_t)(b * Cin) + ci) * HWsz + ioff];
                    acc += v * wp[ci * 9];
                }
            }
        }
    }
    float scale = bng[co] * rsqrtf(1.0f + 1e-5f);
    float r = acc * scale + bnb[co];
    if (res) r += res[idx];
    out[idx] = r;
}

// ---------------- SA: fused 1x1 convs for q, k, c(no-bias) ----------------
// blockIdx.y: 0 -> q (natural layout), 1 -> k (column-contig kT), 2 -> c no-bias (natural)
__global__ void qkc_kernel(const float* __restrict__ x,
                           const float* __restrict__ qw, const float* __restrict__ qb,
                           const float* __restrict__ kw, const float* __restrict__ kb,
                           const float* __restrict__ cw,
                           float* __restrict__ qbuf, float* __restrict__ kT,
                           float* __restrict__ cnb) {
    int p = blockIdx.x * blockDim.x + threadIdx.x;  // pixel 0..9215
    if (p >= BHW) return;
    int b = p / HWsz;
    int hw = p % HWsz;
    float xin[Cch];
#pragma unroll
    for (int ci = 0; ci < Cch; ++ci) xin[ci] = x[((size_t)(b * Cch) + ci) * HWsz + hw];
    int which = blockIdx.y;
    if (which == 0) {
        for (int co = 0; co < Cch; ++co) {
            float acc = qb[co];
#pragma unroll
            for (int ci = 0; ci < Cch; ++ci) acc += xin[ci] * qw[co * Cch + ci];
            qbuf[((size_t)(b * Cch) + co) * HWsz + hw] = acc;
        }
    } else if (which == 1) {
        for (int co = 0; co < Cch; ++co) {
            float acc = kb[co];
#pragma unroll
            for (int ci = 0; ci < Cch; ++ci) acc += xin[ci] * kw[co * Cch + ci];
            kT[(size_t)p * Cch + co] = acc;
        }
    } else {
        for (int co = 0; co < Cch; ++co) {
            float acc = 0.f;
#pragma unroll
            for (int ci = 0; ci < Cch; ++ci) acc += xin[ci] * cw[co * Cch + ci];
            cnb[((size_t)(b * Cch) + co) * HWsz + hw] = acc;
        }
    }
}

// ---------------- score row-scan partials ----------------
// grid (36 row-tiles, 16 col-chunks); thread = one q row (32 contiguous floats).
// Each col-chunk lies entirely within one b group (2304 = 4*576).
__global__ void score_partial_kernel(const float* __restrict__ qbuf,
                                     const float* __restrict__ kT,
                                     float* __restrict__ psum, float* __restrict__ pmax) {
    int i = blockIdx.x * 256 + threadIdx.x;   // row index 0..9215
    int cc = blockIdx.y;                      // 0..15
    float q[32];
    const float4* qp = (const float4*)(qbuf + (size_t)i * 32);
#pragma unroll
    for (int t = 0; t < 8; ++t) {
        float4 v = qp[t];
        q[4 * t] = v.x; q[4 * t + 1] = v.y; q[4 * t + 2] = v.z; q[4 * t + 3] = v.w;
    }
    float sum = 0.f, mx = -1e30f;
    int j0 = cc * CHUNK_COLS;
    for (int j = j0; j < j0 + CHUNK_COLS; ++j) {
        const float* col = kT + (size_t)j * 32;   // wave-uniform -> scalar loads
        float d0 = 0.f, d1 = 0.f, d2 = 0.f, d3 = 0.f;
#pragma unroll
        for (int t = 0; t < 8; ++t) {
            d0 += q[4 * t]     * col[4 * t];
            d1 += q[4 * t + 1] * col[4 * t + 1];
            d2 += q[4 * t + 2] * col[4 * t + 2];
            d3 += q[4 * t + 3] * col[4 * t + 3];
        }
        float d = (d0 + d1) + (d2 + d3);
        sum += d;
        mx = fmaxf(mx, d);
    }
    psum[(size_t)cc * BHW + i] = sum;
    pmax[(size_t)cc * BHW + i] = mx;
}

// combine partials -> logits[i]
__global__ void score_reduce_kernel(const float* __restrict__ psum,
                                    const float* __restrict__ pmax,
                                    float* __restrict__ logits) {
    int i = blockIdx.x * 256 + threadIdx.x;
    if (i >= BHW) return;
    float s = 0.f;
#pragma unroll
    for (int cc = 0; cc < NCHUNK; ++cc) s += psum[(size_t)cc * BHW + i];
    float msum = 0.f;
#pragma unroll
    for (int b = 0; b < 4; ++b) {
        float m = -1e30f;
#pragma unroll
        for (int k = 0; k < 4; ++k) m = fmaxf(m, pmax[(size_t)(b * 4 + k) * BHW + i]);
        msum += m;
    }
    // logits = (mean_b max + mean_{b,hw} dot) / sqrt(C)
    logits[i] = (msum * 0.25f + s * (1.0f / (float)BHW)) * 0.17677669529663687f;
}

// softmax over HW per b -> xco
__global__ void softmax_kernel(const float* __restrict__ logits, float* __restrict__ xco) {
    int b = blockIdx.x;
    int tid = threadIdx.x;
    __shared__ float red[256];
    const float* l = logits + (size_t)b * HWsz;
    float m = -1e30f;
    for (int h = tid; h < HWsz; h += 256) m = fmaxf(m, l[h]);
    red[tid] = m; __syncthreads();
    for (int s = 128; s > 0; s >>= 1) { if (tid < s) red[tid] = fmaxf(red[tid], red[tid + s]); __syncthreads(); }
    m = red[0]; __syncthreads();
    float s = 0.f;
    for (int h = tid; h < HWsz; h += 256) s += expf(l[h] - m);
    red[tid] = s; __syncthreads();
    for (int st = 128; st > 0; st >>= 1) { if (tid < st) red[tid] += red[tid + st]; __syncthreads(); }
    float inv = 1.0f / red[0];
    for (int h = tid; h < HWsz; h += 256) xco[(size_t)b * HWsz + h] = expf(l[h] - m) * inv;
}

// out[b,c,hw] = cnb[b,c,hw] * xco[b,hw] + cb[c]
__global__ void sa_apply_kernel(const float* __restrict__ cnb, const float* __restrict__ xco,
                                const float* __restrict__ cb, float* __restrict__ out) {
    int idx = blockIdx.x * blockDim.x + threadIdx.x;
    if (idx >= Bsz * Cch * HWsz) return;
    int hw = idx % HWsz;
    int c = (idx / HWsz) % Cch;
    int b = idx / (HWsz * Cch);
    out[idx] = cnb[idx] * xco[(size_t)b * HWsz + hw] + cb[c];
}

extern "C" void kernel_launch(void* const* d_in, const int* in_sizes, int n_in,
                              void* d_out, int out_size, void* d_ws, size_t ws_size,
                              hipStream_t stream) {
    const float* x1      = (const float*)d_in[0];
    const float* x2      = (const float*)d_in[1];
    const float* x3      = (const float*)d_in[2];
    const float* conv1_w = (const float*)d_in[3];
    const float* bn1_g   = (const float*)d_in[4];
    const float* bn1_b   = (const float*)d_in[5];
    const float* conv4_w = (const float*)d_in[6];
    const float* bn4_g   = (const float*)d_in[7];
    const float* bn4_b   = (const float*)d_in[8];
    const float* conv5_w = (const float*)d_in[9];
    const float* bn5_g   = (const float*)d_in[10];
    const float* bn5_b   = (const float*)d_in[11];
    const float* convfs_w= (const float*)d_in[12];
    const float* bnfs_g  = (const float*)d_in[13];
    const float* bnfs_b  = (const float*)d_in[14];
    const float* saq_w   = (const float*)d_in[15];
    const float* saq_b   = (const float*)d_in[16];
    const float* sak_w   = (const float*)d_in[17];
    const float* sak_b   = (const float*)d_in[18];
    const float* sac6_w  = (const float*)d_in[19];
    const float* sac6_b  = (const float*)d_in[20];

    float* ws = (float*)d_ws;
    const size_t TEN = (size_t)Bsz * Cch * HWsz;  // 294912
    float* cat    = ws;                    // B*96*HW = 884736
    float* f1     = cat + (size_t)Bsz * CIN_CAT * HWsz;
    float* f_s_1  = f1 + TEN;
    float* fg     = f_s_1 + TEN;
    float* fs     = fg + TEN;
    float* sfs    = fs + TEN;
    float* fgl    = sfs + TEN;
    float* t1     = fgl + TEN;
    float* qbuf   = t1 + TEN;
    float* kT     = qbuf + TEN;
    float* cnb    = kT + TEN;
    float* logits = cnb + TEN;             // 9216
    float* xco    = logits + BHW;          // 9216
    float* psum   = xco + BHW;             // 16*9216
    float* pmax   = psum + (size_t)NCHUNK * BHW;

    const int TPB = 256;
    const int GRID_TEN = (int)((TEN + TPB - 1) / TPB);   // 1152

    // 1. f3 = resize(x3, 192->48) into cat ch[0:32)
    resize_kernel<<<GRID_TEN, TPB, 0, stream>>>(x3, cat, 192, 192, 192, 192 * 192, 0,
                                                191.0f / 47.0f, 191.0f / 47.0f, CIN_CAT, 0);
    // 2. f2 = resize(x2, 96->48) into cat ch[32:64)
    resize_kernel<<<GRID_TEN, TPB, 0, stream>>>(x2, cat, 96, 96, 96, 96 * 96, 0,
                                                95.0f / 47.0f, 95.0f / 47.0f, CIN_CAT, 32);
    // 3. x1 into cat ch[64:96)
    copy_x1_kernel<<<GRID_TEN, TPB, 0, stream>>>(x1, cat);
    // 4. f1 = bn1(conv1(cat))
    conv3x3_kernel<<<GRID_TEN, TPB, 0, stream>>>(cat, nullptr, conv1_w, bn1_g, bn1_b,
                                                 nullptr, f1, CIN_CAT, Cch);
    // 5. f_s_1 = resize(f1[:, :, 32:48, 32:48], 16->48)  (chunk idx is always 8)
    resize_kernel<<<GRID_TEN, TPB, 0, stream>>>(f1, f_s_1, 16, 16, Ww, HWsz, 32 * Ww + 32,
                                                15.0f / 47.0f, 15.0f / 47.0f, Cch, 0);

    // SA macro: x -> out
    auto run_sa = [&](const float* xin, float* outp) {
        dim3 g1((BHW + TPB - 1) / TPB, 3);
        qkc_kernel<<<g1, TPB, 0, stream>>>(xin, saq_w, saq_b, sak_w, sak_b, sac6_w,
                                           qbuf, kT, cnb);
        dim3 g2(BHW / 256, NCHUNK);
        score_partial_kernel<<<g2, 256, 0, stream>>>(qbuf, kT, psum, pmax);
        score_reduce_kernel<<<BHW / 256, 256, 0, stream>>>(psum, pmax, logits);
        softmax_kernel<<<Bsz, 256, 0, stream>>>(logits, xco);
        sa_apply_kernel<<<GRID_TEN, TPB, 0, stream>>>(cnb, xco, sac6_b, outp);
    };

    // 6-8. fg = sa(f1); fs = sa(f_s_1); sfs = sa(fs)
    run_sa(f1, fg);
    run_sa(f_s_1, fs);
    run_sa(fs, sfs);

    // 9. fgl = bnfs(convfs(fg + sfs))
    conv3x3_kernel<<<GRID_TEN, TPB, 0, stream>>>(fg, sfs, convfs_w, bnfs_g, bnfs_b,
                                                 nullptr, fgl, Cch, Cch);
    // 10. t1 = bn4(conv4(fgl)) + fg
    conv3x3_kernel<<<GRID_TEN, TPB, 0, stream>>>(fgl, nullptr, conv4_w, bn4_g, bn4_b,
                                                 fg, t1, Cch, Cch);
    // 11. out = bn5(conv5(t1))   (B,1,48,48)
    conv3x3_kernel<<<(Bsz * HWsz + TPB - 1) / TPB, TPB, 0, stream>>>(
        t1, nullptr, conv5_w, bn5_g, bn5_b, nullptr, (float*)d_out, Cch, 1);
}

// Round 3
// 629.307 us; speedup vs baseline: 1.8558x; 1.8558x over previous
//
#include <hip/hip_runtime.h>
#include <math.h>

#define Bsz 4
#define Cch 32
#define Hh 48
#define Ww 48
#define HWsz 2304          // 48*48
#define BHW 9216           // 4*2304
#define CIN_CAT 96
#define NSPLIT 16          // column splits for max partials (4 per b-group)
#define TILES_PER_SPLIT 36 // 576 col-tiles / 16

typedef __bf16 bf16_t;
typedef __bf16 bf16x8 __attribute__((ext_vector_type(8)));
typedef float f32x4 __attribute__((ext_vector_type(4)));

// ---------------- bilinear resize, align_corners=True ----------------
__global__ void resize_kernel(const float* __restrict__ in, float* __restrict__ out,
                              int inH, int inW, int rowStride, int chanStride, int baseOff,
                              float scaleY, float scaleX, int outCtot, int chanOff) {
    int idx = blockIdx.x * blockDim.x + threadIdx.x;
    if (idx >= Bsz * Cch * HWsz) return;
    int x = idx % Ww;
    int y = (idx / Ww) % Hh;
    int c = (idx / HWsz) % Cch;
    int b = idx / (HWsz * Cch);
    float fy = y * scaleY;
    float fx = x * scaleX;
    int y0 = (int)floorf(fy); int x0 = (int)floorf(fx);
    y0 = min(y0, inH - 1); x0 = min(x0, inW - 1);
    int y1 = min(y0 + 1, inH - 1); int x1 = min(x0 + 1, inW - 1);
    float wy = fy - (float)y0, wx = fx - (float)x0;
    const float* src = in + (size_t)(b * Cch + c) * chanStride + baseOff;
    float v00 = src[y0 * rowStride + x0];
    float v01 = src[y0 * rowStride + x1];
    float v10 = src[y1 * rowStride + x0];
    float v11 = src[y1 * rowStride + x1];
    float top = v00 * (1.f - wx) + v01 * wx;
    float bot = v10 * (1.f - wx) + v11 * wx;
    float r = top * (1.f - wy) + bot * wy;
    out[((size_t)(b * outCtot) + c + chanOff) * HWsz + y * Ww + x] = r;
}

// copy x1 (B,32,HW) into cat channels [64..96)
__global__ void copy_x1_kernel(const float* __restrict__ x1, float* __restrict__ cat) {
    int idx = blockIdx.x * blockDim.x + threadIdx.x;
    if (idx >= Bsz * Cch * HWsz) return;
    int hw = idx % HWsz;
    int c = (idx / HWsz) % Cch;
    int b = idx / (HWsz * Cch);
    cat[((size_t)(b * CIN_CAT) + 64 + c) * HWsz + hw] = x1[idx];
}

// ---------------- 3x3 conv, pad 1, fused BN (+optional input add, output residual) ----
__global__ void conv3x3_kernel(const float* __restrict__ in, const float* __restrict__ in2,
                               const float* __restrict__ w, const float* __restrict__ bng,
                               const float* __restrict__ bnb, const float* __restrict__ res,
                               float* __restrict__ out, int Cin, int Cout) {
    int idx = blockIdx.x * blockDim.x + threadIdx.x;
    int total = Bsz * Cout * HWsz;
    if (idx >= total) return;
    int x = idx % Ww;
    int y = (idx / Ww) % Hh;
    int co = (idx / HWsz) % Cout;
    int b = idx / (HWsz * Cout);
    bool has2 = (in2 != nullptr);
    float acc = 0.f;
#pragma unroll
    for (int ky = 0; ky < 3; ++ky) {
        int iy = y + ky - 1;
        if (iy < 0 || iy >= Hh) continue;
#pragma unroll
        for (int kx = 0; kx < 3; ++kx) {
            int ix = x + kx - 1;
            if (ix < 0 || ix >= Ww) continue;
            int ioff = iy * Ww + ix;
            const float* wp = w + ((size_t)co * Cin) * 9 + ky * 3 + kx;
            if (has2) {
                for (int ci = 0; ci < Cin; ++ci) {
                    float v = in[((size_t)(b * Cin) + ci) * HWsz + ioff]
                            + in2[((size_t)(b * Cin) + ci) * HWsz + ioff];
                    acc += v * wp[ci * 9];
                }
            } else {
                for (int ci = 0; ci < Cin; ++ci) {
                    float v = in[((size_t)(b * Cin) + ci) * HWsz + ioff];
                    acc += v * wp[ci * 9];
                }
            }
        }
    }
    float scale = bng[co] * rsqrtf(1.0f + 1e-5f);
    float r = acc * scale + bnb[co];
    if (res) r += res[idx];
    out[idx] = r;
}

// ---------------- SA: fused 1x1 convs for q, k, c(no-bias) ----------------
// blockIdx.y: 0 -> q (fp32 natural + bf16 hi/lo), 1 -> k (col-contig kT fp32 + hi/lo),
//             2 -> c no-bias (natural fp32)
__global__ void qkc_kernel(const float* __restrict__ x,
                           const float* __restrict__ qw, const float* __restrict__ qb,
                           const float* __restrict__ kw, const float* __restrict__ kb,
                           const float* __restrict__ cw,
                           float* __restrict__ qbuf, float* __restrict__ kT,
                           float* __restrict__ cnb,
                           bf16_t* __restrict__ qhi, bf16_t* __restrict__ qlo,
                           bf16_t* __restrict__ khi, bf16_t* __restrict__ klo) {
    int p = blockIdx.x * blockDim.x + threadIdx.x;  // pixel 0..9215
    if (p >= BHW) return;
    int b = p / HWsz;
    int hw = p % HWsz;
    float xin[Cch];
#pragma unroll
    for (int ci = 0; ci < Cch; ++ci) xin[ci] = x[((size_t)(b * Cch) + ci) * HWsz + hw];
    int which = blockIdx.y;
    if (which == 0) {
        for (int co = 0; co < Cch; ++co) {
            float acc = qb[co];
#pragma unroll
            for (int ci = 0; ci < Cch; ++ci) acc += xin[ci] * qw[co * Cch + ci];
            size_t f = ((size_t)(b * Cch) + co) * HWsz + hw;
            qbuf[f] = acc;
            bf16_t h = (bf16_t)acc;
            qhi[f] = h;
            qlo[f] = (bf16_t)(acc - (float)h);
        }
    } else if (which == 1) {
        for (int co = 0; co < Cch; ++co) {
            float acc = kb[co];
#pragma unroll
            for (int ci = 0; ci < Cch; ++ci) acc += xin[ci] * kw[co * Cch + ci];
            size_t f = (size_t)p * Cch + co;
            kT[f] = acc;
            bf16_t h = (bf16_t)acc;
            khi[f] = h;
            klo[f] = (bf16_t)(acc - (float)h);
        }
    } else {
        for (int co = 0; co < Cch; ++co) {
            float acc = 0.f;
#pragma unroll
            for (int ci = 0; ci < Cch; ++ci) acc += xin[ci] * cw[co * Cch + ci];
            cnb[((size_t)(b * Cch) + co) * HWsz + hw] = acc;
        }
    }
}

// ---------------- ksum: column sums of kT (exact fp32, for the mean term) ----------
__global__ void ksum_kernel(const float* __restrict__ kT, float* __restrict__ ksum) {
    int c = blockIdx.x;   // 0..31
    int tid = threadIdx.x;
    __shared__ float red[256];
    float s = 0.f;
    for (int j = tid; j < BHW; j += 256) s += kT[(size_t)j * Cch + c];
    red[tid] = s; __syncthreads();
    for (int st = 128; st > 0; st >>= 1) { if (tid < st) red[tid] += red[tid + st]; __syncthreads(); }
    if (tid == 0) ksum[c] = red[0];
}

// ---------------- score max-scan via MFMA (split-bf16: hi*hi + hi*lo + lo*hi) -------
// grid (144 row-tile groups, 16 col splits), block 256 = 4 waves.
// wave w owns row-tile rt = bx*4+w (16 rows), scans 36 col-tiles (= 576 cols,
// entirely inside one b-group since 2304 = 4*576).
__global__ void score_mfma_kernel(const bf16_t* __restrict__ qhi, const bf16_t* __restrict__ qlo,
                                  const bf16_t* __restrict__ khi, const bf16_t* __restrict__ klo,
                                  float* __restrict__ pmax) {
    int wave = threadIdx.x >> 6;
    int lane = threadIdx.x & 63;
    int rt = blockIdx.x * 4 + wave;   // 0..575
    int cs = blockIdx.y;              // 0..15
    int lrow = lane & 15;
    int lk = lane >> 4;
    size_t aoff = (size_t)(rt * 16 + lrow) * Cch + lk * 8;
    bf16x8 ahi = *(const bf16x8*)(qhi + aoff);
    bf16x8 alo = *(const bf16x8*)(qlo + aoff);
    f32x4 mx = {-1e30f, -1e30f, -1e30f, -1e30f};
    int ct0 = cs * TILES_PER_SPLIT;
    for (int ct = ct0; ct < ct0 + TILES_PER_SPLIT; ++ct) {
        size_t boff = (size_t)(ct * 16 + lrow) * Cch + lk * 8;
        bf16x8 bhi = *(const bf16x8*)(khi + boff);
        bf16x8 blo = *(const bf16x8*)(klo + boff);
        f32x4 d = {0.f, 0.f, 0.f, 0.f};
        d = __builtin_amdgcn_mfma_f32_16x16x32_bf16(ahi, bhi, d, 0, 0, 0);
        d = __builtin_amdgcn_mfma_f32_16x16x32_bf16(ahi, blo, d, 0, 0, 0);
        d = __builtin_amdgcn_mfma_f32_16x16x32_bf16(alo, bhi, d, 0, 0, 0);
#pragma unroll
        for (int r = 0; r < 4; ++r) mx[r] = fmaxf(mx[r], d[r]);
    }
    // reduce max across the 16 column-lanes of each row group
#pragma unroll
    for (int off = 1; off < 16; off <<= 1) {
#pragma unroll
        for (int r = 0; r < 4; ++r) {
            float o = __shfl_xor(mx[r], off, 64);
            mx[r] = fmaxf(mx[r], o);
        }
    }
    if (lrow == 0) {
#pragma unroll
        for (int r = 0; r < 4; ++r) {
            int row = rt * 16 + lk * 4 + r;   // C/D layout: row=(lane>>4)*4+reg
            pmax[(size_t)cs * BHW + row] = mx[r];
        }
    }
}

// ---------------- logits: mean_b(max) + q.ksum/BHW, scaled ----------------
__global__ void logits_kernel(const float* __restrict__ qbuf, const float* __restrict__ ksum,
                              const float* __restrict__ pmax, float* __restrict__ logits) {
    __shared__ float ks[Cch];
    if (threadIdx.x < Cch) ks[threadIdx.x] = ksum[threadIdx.x];
    __syncthreads();
    int i = blockIdx.x * 256 + threadIdx.x;
    if (i >= BHW) return;
    float msum = 0.f;
#pragma unroll
    for (int b = 0; b < 4; ++b) {
        float m = -1e30f;
#pragma unroll
        for (int k = 0; k < 4; ++k) m = fmaxf(m, pmax[(size_t)(b * 4 + k) * BHW + i]);
        msum += m;
    }
    float dot = 0.f;
    const float4* qp = (const float4*)(qbuf + (size_t)i * Cch);
#pragma unroll
    for (int t = 0; t < 8; ++t) {
        float4 v = qp[t];
        dot += v.x * ks[4 * t] + v.y * ks[4 * t + 1] + v.z * ks[4 * t + 2] + v.w * ks[4 * t + 3];
    }
    logits[i] = (msum * 0.25f + dot * (1.0f / (float)BHW)) * 0.17677669529663687f;
}

// softmax over HW per b -> xco
__global__ void softmax_kernel(const float* __restrict__ logits, float* __restrict__ xco) {
    int b = blockIdx.x;
    int tid = threadIdx.x;
    __shared__ float red[256];
    const float* l = logits + (size_t)b * HWsz;
    float m = -1e30f;
    for (int h = tid; h < HWsz; h += 256) m = fmaxf(m, l[h]);
    red[tid] = m; __syncthreads();
    for (int s = 128; s > 0; s >>= 1) { if (tid < s) red[tid] = fmaxf(red[tid], red[tid + s]); __syncthreads(); }
    m = red[0]; __syncthreads();
    float s = 0.f;
    for (int h = tid; h < HWsz; h += 256) s += expf(l[h] - m);
    red[tid] = s; __syncthreads();
    for (int st = 128; st > 0; st >>= 1) { if (tid < st) red[tid] += red[tid + st]; __syncthreads(); }
    float inv = 1.0f / red[0];
    for (int h = tid; h < HWsz; h += 256) xco[(size_t)b * HWsz + h] = expf(l[h] - m) * inv;
}

// out[b,c,hw] = cnb[b,c,hw] * xco[b,hw] + cb[c]
__global__ void sa_apply_kernel(const float* __restrict__ cnb, const float* __restrict__ xco,
                                const float* __restrict__ cb, float* __restrict__ out) {
    int idx = blockIdx.x * blockDim.x + threadIdx.x;
    if (idx >= Bsz * Cch * HWsz) return;
    int hw = idx % HWsz;
    int c = (idx / HWsz) % Cch;
    int b = idx / (HWsz * Cch);
    out[idx] = cnb[idx] * xco[(size_t)b * HWsz + hw] + cb[c];
}

extern "C" void kernel_launch(void* const* d_in, const int* in_sizes, int n_in,
                              void* d_out, int out_size, void* d_ws, size_t ws_size,
                              hipStream_t stream) {
    const float* x1      = (const float*)d_in[0];
    const float* x2      = (const float*)d_in[1];
    const float* x3      = (const float*)d_in[2];
    const float* conv1_w = (const float*)d_in[3];
    const float* bn1_g   = (const float*)d_in[4];
    const float* bn1_b   = (const float*)d_in[5];
    const float* conv4_w = (const float*)d_in[6];
    const float* bn4_g   = (const float*)d_in[7];
    const float* bn4_b   = (const float*)d_in[8];
    const float* conv5_w = (const float*)d_in[9];
    const float* bn5_g   = (const float*)d_in[10];
    const float* bn5_b   = (const float*)d_in[11];
    const float* convfs_w= (const float*)d_in[12];
    const float* bnfs_g  = (const float*)d_in[13];
    const float* bnfs_b  = (const float*)d_in[14];
    const float* saq_w   = (const float*)d_in[15];
    const float* saq_b   = (const float*)d_in[16];
    const float* sak_w   = (const float*)d_in[17];
    const float* sak_b   = (const float*)d_in[18];
    const float* sac6_w  = (const float*)d_in[19];
    const float* sac6_b  = (const float*)d_in[20];

    float* ws = (float*)d_ws;
    const size_t TEN = (size_t)Bsz * Cch * HWsz;  // 294912
    float* cat    = ws;                    // B*96*HW = 884736
    float* f1     = cat + (size_t)Bsz * CIN_CAT * HWsz;
    float* f_s_1  = f1 + TEN;
    float* fg     = f_s_1 + TEN;
    float* fs     = fg + TEN;
    float* sfs    = fs + TEN;
    float* fgl    = sfs + TEN;
    float* t1     = fgl + TEN;
    float* qbuf   = t1 + TEN;
    float* kT     = qbuf + TEN;
    float* cnb    = kT + TEN;
    float* logits = cnb + TEN;             // 9216
    float* xco    = logits + BHW;          // 9216
    float* pmax   = xco + BHW;             // 16*9216
    float* ksum   = pmax + (size_t)NSPLIT * BHW;  // 32
    bf16_t* qhi   = (bf16_t*)(ksum + 64);  // 294912 bf16 each
    bf16_t* qlo   = qhi + TEN;
    bf16_t* khi   = qlo + TEN;
    bf16_t* klo   = khi + TEN;

    const int TPB = 256;
    const int GRID_TEN = (int)((TEN + TPB - 1) / TPB);   // 1152

    // 1. f3 = resize(x3, 192->48) into cat ch[0:32)
    resize_kernel<<<GRID_TEN, TPB, 0, stream>>>(x3, cat, 192, 192, 192, 192 * 192, 0,
                                                191.0f / 47.0f, 191.0f / 47.0f, CIN_CAT, 0);
    // 2. f2 = resize(x2, 96->48) into cat ch[32:64)
    resize_kernel<<<GRID_TEN, TPB, 0, stream>>>(x2, cat, 96, 96, 96, 96 * 96, 0,
                                                95.0f / 47.0f, 95.0f / 47.0f, CIN_CAT, 32);
    // 3. x1 into cat ch[64:96)
    copy_x1_kernel<<<GRID_TEN, TPB, 0, stream>>>(x1, cat);
    // 4. f1 = bn1(conv1(cat))
    conv3x3_kernel<<<GRID_TEN, TPB, 0, stream>>>(cat, nullptr, conv1_w, bn1_g, bn1_b,
                                                 nullptr, f1, CIN_CAT, Cch);
    // 5. f_s_1 = resize(f1[:, :, 32:48, 32:48], 16->48)  (chunk idx is always 8)
    resize_kernel<<<GRID_TEN, TPB, 0, stream>>>(f1, f_s_1, 16, 16, Ww, HWsz, 32 * Ww + 32,
                                                15.0f / 47.0f, 15.0f / 47.0f, Cch, 0);

    // SA macro: x -> out
    auto run_sa = [&](const float* xin, float* outp) {
        dim3 g1((BHW + TPB - 1) / TPB, 3);
        qkc_kernel<<<g1, TPB, 0, stream>>>(xin, saq_w, saq_b, sak_w, sak_b, sac6_w,
                                           qbuf, kT, cnb, qhi, qlo, khi, klo);
        ksum_kernel<<<Cch, 256, 0, stream>>>(kT, ksum);
        dim3 g2(144, NSPLIT);
        score_mfma_kernel<<<g2, 256, 0, stream>>>(qhi, qlo, khi, klo, pmax);
        logits_kernel<<<BHW / 256, 256, 0, stream>>>(qbuf, ksum, pmax, logits);
        softmax_kernel<<<Bsz, 256, 0, stream>>>(logits, xco);
        sa_apply_kernel<<<GRID_TEN, TPB, 0, stream>>>(cnb, xco, sac6_b, outp);
    };

    // 6-8. fg = sa(f1); fs = sa(f_s_1); sfs = sa(fs)
    run_sa(f1, fg);
    run_sa(f_s_1, fs);
    run_sa(fs, sfs);

    // 9. fgl = bnfs(convfs(fg + sfs))
    conv3x3_kernel<<<GRID_TEN, TPB, 0, stream>>>(fg, sfs, convfs_w, bnfs_g, bnfs_b,
                                                 nullptr, fgl, Cch, Cch);
    // 10. t1 = bn4(conv4(fgl)) + fg
    conv3x3_kernel<<<GRID_TEN, TPB, 0, stream>>>(fgl, nullptr, conv4_w, bn4_g, bn4_b,
                                                 fg, t1, Cch, Cch);
    // 11. out = bn5(conv5(t1))   (B,1,48,48)
    conv3x3_kernel<<<(Bsz * HWsz + TPB - 1) / TPB, TPB, 0, stream>>>(
        t1, nullptr, conv5_w, bn5_g, bn5_b, nullptr, (float*)d_out, Cch, 1);
}